// Round 1
// baseline (287.810 us; speedup 1.0000x reference)
//
#include <hip/hip_runtime.h>
#include <hip/hip_bf16.h>
#include <math.h>

typedef __bf16 bf16_t;
typedef bf16_t bf16x8 __attribute__((ext_vector_type(8)));
typedef bf16_t bf16x4 __attribute__((ext_vector_type(4)));
typedef float  f32x4  __attribute__((ext_vector_type(4)));

#define NB    2
#define SEQ   2048
#define DIM   2048
#define NHEAD 16
#define NKVH  4
#define HDIM  128
#define WINSZ 256
#define KVD   (NKVH*HDIM)   // 512
#define MROWS (NB*SEQ)      // 4096

// ---- async global->LDS, 16B per lane, dest = wave-uniform base + lane*16 ----
__device__ __forceinline__ void async_copy16(const void* g, void* lds) {
    __builtin_amdgcn_global_load_lds(
        (const __attribute__((address_space(1))) void*)g,
        (__attribute__((address_space(3))) void*)lds,
        16, 0, 0);
}

// ---- f32 -> bf16 elementwise (for x) ----
__global__ __launch_bounds__(256) void cvt_f32_bf16(const float* __restrict__ in,
                                                    bf16_t* __restrict__ out, int n) {
    int i = (blockIdx.x * 256 + threadIdx.x) * 4;
    if (i >= n) return;
    float4 v = *(const float4*)(in + i);
    bf16x4 o;
    o[0] = (bf16_t)v.x; o[1] = (bf16_t)v.y; o[2] = (bf16_t)v.z; o[3] = (bf16_t)v.w;
    *(bf16x4*)(out + i) = o;
}

// ---- W [K,N] f32  ->  W^T [N,K] bf16 ----
__global__ __launch_bounds__(256) void transpose_cvt(const float* __restrict__ in,
                                                     bf16_t* __restrict__ out, int K, int N) {
    __shared__ float tile[32][33];
    int tx = threadIdx.x & 31, ty = threadIdx.x >> 5;
    int n0 = blockIdx.x * 32, k0 = blockIdx.y * 32;
    for (int r = ty; r < 32; r += 8)
        tile[r][tx] = in[(size_t)(k0 + r) * N + n0 + tx];
    __syncthreads();
    for (int r = ty; r < 32; r += 8)
        out[(size_t)(n0 + r) * K + k0 + tx] = (bf16_t)tile[tx][r];
}

// ---- C[M,N] = (A[M,K] @ Bt[N,K]^T + bias) * scale ; m97 128x128 structure ----
template <typename OutT>
__global__ __launch_bounds__(256) void gemm_bt(const bf16_t* __restrict__ A,
                                               const bf16_t* __restrict__ Bt,
                                               const float* __restrict__ bias,
                                               OutT* __restrict__ C,
                                               int M, int N, int K, float scale) {
    __shared__ bf16_t As[128 * 32];
    __shared__ bf16_t Bs[128 * 32];
    const int tid  = threadIdx.x;
    const int wave = tid >> 6;
    const int lane = tid & 63;
    const int lg = lane >> 4, lc = lane & 15;
    const int wr = wave >> 1, wc = wave & 1;
    const long brow = (long)blockIdx.y * 128;
    const long bcol = (long)blockIdx.x * 128;
    const int srow = lane >> 2;        // row within 16-row staging chunk
    const int scol = (lane & 3) * 8;   // elem offset within 32-elem row

    f32x4 acc[4][4] = {};

    for (int k0 = 0; k0 < K; k0 += 32) {
        __syncthreads();   // previous frag reads done before LDS overwrite
#pragma unroll
        for (int q = 0; q < 2; ++q) {
            int chunk = wave * 2 + q;   // 8 chunks x 16 rows = 128 rows
            const bf16_t* ga = A  + (brow + chunk * 16 + srow) * (long)K + k0 + scol;
            const bf16_t* gb = Bt + (bcol + chunk * 16 + srow) * (long)K + k0 + scol;
            async_copy16(ga, As + chunk * 512);
            async_copy16(gb, Bs + chunk * 512);
        }
        __syncthreads();   // vmcnt drain: tiles resident
        bf16x8 af[4], bfr[4];
#pragma unroll
        for (int m = 0; m < 4; ++m)
            af[m] = *(const bf16x8*)(As + (wr * 64 + m * 16 + lc) * 32 + lg * 8);
#pragma unroll
        for (int n = 0; n < 4; ++n)
            bfr[n] = *(const bf16x8*)(Bs + (wc * 64 + n * 16 + lc) * 32 + lg * 8);
#pragma unroll
        for (int m = 0; m < 4; ++m)
#pragma unroll
            for (int n = 0; n < 4; ++n)
                acc[m][n] = __builtin_amdgcn_mfma_f32_16x16x32_bf16(af[m], bfr[n], acc[m][n], 0, 0, 0);
    }

#pragma unroll
    for (int n = 0; n < 4; ++n) {
        int gc = (int)bcol + wc * 64 + n * 16 + lc;
        float bv = bias[gc];
#pragma unroll
        for (int m = 0; m < 4; ++m) {
            long gr = brow + wr * 64 + m * 16 + 4 * lg;
#pragma unroll
            for (int r = 0; r < 4; ++r) {
                float v = (acc[m][n][r] + bv) * scale;
                C[(gr + r) * N + gc] = (OutT)v;
            }
        }
    }
}

// ---- sliding-window GQA flash attention; 1 wave per (b, h, 16-row q-tile) ----
__global__ __launch_bounds__(64) void attn_kernel(const bf16_t* __restrict__ Qb,
                                                  const bf16_t* __restrict__ Kb,
                                                  const bf16_t* __restrict__ Vb,
                                                  bf16_t* __restrict__ Ob) {
    __shared__ bf16_t Vls[32 * 128];   // V tile  [32 j][128 d]
    __shared__ bf16_t Pls[32 * 16];    // P^T     [32 j][16 q]
    const int lane = threadIdx.x;
    const int lg = lane >> 4, lc = lane & 15;
    const int ti = blockIdx.x;     // q-tile (16 rows)
    const int h  = blockIdx.y;
    const int b  = blockIdx.z;
    const int g  = h >> 2;         // kv group
    const int i0 = ti * 16;
    const int irow = i0 + lc;      // this lane's q row

    // Q fragments (already scaled by 1/sqrt(HD)): Q[irow][k], k = kk*32 + lg*8 + e
    bf16x8 qf[4];
    {
        const bf16_t* qp = Qb + ((size_t)(b * SEQ) + irow) * DIM + h * HDIM + lg * 8;
#pragma unroll
        for (int kk = 0; kk < 4; ++kk) qf[kk] = *(const bf16x8*)(qp + kk * 32);
    }

    float m_run = -1e30f, l_run = 0.f;
    f32x4 oacc[8] = {};   // O^T frags: row d = c*16 + 4*lg + r, col q = lc

    int jlo = i0 - (WINSZ - 1); if (jlo < 0) jlo = 0;
    const int jb_lo = jlo >> 5;
    const int jb_hi = (i0 + 15) >> 5;

    for (int jb = jb_lo; jb <= jb_hi; ++jb) {
        const int j0 = jb * 32;
        __syncthreads();   // previous PV reads done before restage
        // stage V tile (32x128 bf16 = 8KB), overlaps with QK^T below
#pragma unroll
        for (int q = 0; q < 8; ++q) {
            int row = q * 4 + (lane >> 4);
            int ce  = (lane & 15) * 8;
            async_copy16(Vb + ((size_t)(b * SEQ) + j0 + row) * KVD + g * HDIM + ce,
                         Vls + q * 512);
        }
        // S^T = K . Q^T  (two 16-j subtiles): D row = local j, col = q
        f32x4 s[2];
#pragma unroll
        for (int t = 0; t < 2; ++t) {
            const bf16_t* kp = Kb + ((size_t)(b * SEQ) + j0 + t * 16 + lc) * KVD + g * HDIM + lg * 8;
            f32x4 sv = {};
#pragma unroll
            for (int kk = 0; kk < 4; ++kk) {
                bf16x8 kf = *(const bf16x8*)(kp + kk * 32);
                sv = __builtin_amdgcn_mfma_f32_16x16x32_bf16(kf, qf[kk], sv, 0, 0, 0);
            }
            s[t] = sv;
        }
        // mask + tile row-max (rows = q = lc; reduce across lane groups)
        float tmax = -1e30f;
#pragma unroll
        for (int t = 0; t < 2; ++t)
#pragma unroll
            for (int r = 0; r < 4; ++r) {
                int j = j0 + t * 16 + 4 * lg + r;
                bool keep = (j <= irow) && (j >= irow - (WINSZ - 1));
                if (!keep) s[t][r] = -1e30f;
                tmax = fmaxf(tmax, s[t][r]);
            }
        tmax = fmaxf(tmax, __shfl_xor(tmax, 16, 64));
        tmax = fmaxf(tmax, __shfl_xor(tmax, 32, 64));
        float m_new = fmaxf(m_run, tmax);
        float resc  = __expf(m_run - m_new);   // ==1 when nothing seen yet (acc=0, safe)
        float psum = 0.f;
#pragma unroll
        for (int t = 0; t < 2; ++t)
#pragma unroll
            for (int r = 0; r < 4; ++r) {
                float sv = s[t][r];
                float p  = (sv < -5e29f) ? 0.f : __expf(sv - m_new);  // masked -> exactly 0
                psum += p;
                Pls[(t * 16 + 4 * lg + r) * 16 + lc] = (bf16_t)p;
            }
        psum += __shfl_xor(psum, 16, 64);
        psum += __shfl_xor(psum, 32, 64);
        l_run = l_run * resc + psum;
        m_run = m_new;
#pragma unroll
        for (int c = 0; c < 8; ++c) {
            oacc[c][0] *= resc; oacc[c][1] *= resc; oacc[c][2] *= resc; oacc[c][3] *= resc;
        }
        __syncthreads();   // V staged (vmcnt) + P written (lgkm)
        // PV: O^T += V^T . P^T   (A = V^T frags, B = P^T frag, K=32)
        bf16x8 pf;
#pragma unroll
        for (int e = 0; e < 8; ++e) pf[e] = Pls[(lg * 8 + e) * 16 + lc];
#pragma unroll
        for (int c = 0; c < 8; ++c) {
            bf16x8 vf;
#pragma unroll
            for (int e = 0; e < 8; ++e) vf[e] = Vls[(lg * 8 + e) * 128 + c * 16 + lc];
            oacc[c] = __builtin_amdgcn_mfma_f32_16x16x32_bf16(vf, pf, oacc[c], 0, 0, 0);
        }
    }

    const float inv = 1.f / l_run;
#pragma unroll
    for (int c = 0; c < 8; ++c) {
        bf16x4 ov;
#pragma unroll
        for (int r = 0; r < 4; ++r) ov[r] = (bf16_t)(oacc[c][r] * inv);
        *(bf16x4*)(Ob + ((size_t)(b * SEQ) + irow) * DIM + h * HDIM + c * 16 + lg * 4) = ov;
    }
}

extern "C" void kernel_launch(void* const* d_in, const int* in_sizes, int n_in,
                              void* d_out, int out_size, void* d_ws, size_t ws_size,
                              hipStream_t stream) {
    const float* x  = (const float*)d_in[0];
    const float* Wq = (const float*)d_in[1];
    const float* bq = (const float*)d_in[2];
    const float* Wk = (const float*)d_in[3];
    const float* bk = (const float*)d_in[4];
    const float* Wv = (const float*)d_in[5];
    const float* bv = (const float*)d_in[6];
    const float* Wo = (const float*)d_in[7];
    const float* bo = (const float*)d_in[8];
    float* out = (float*)d_out;

    char* ws = (char*)d_ws;
    bf16_t* xb  = (bf16_t*)ws; ws += (size_t)MROWS * DIM * 2;
    bf16_t* WqT = (bf16_t*)ws; ws += (size_t)DIM * DIM * 2;
    bf16_t* WkT = (bf16_t*)ws; ws += (size_t)KVD * DIM * 2;
    bf16_t* WvT = (bf16_t*)ws; ws += (size_t)KVD * DIM * 2;
    bf16_t* WoT = (bf16_t*)ws; ws += (size_t)DIM * DIM * 2;
    bf16_t* Qb  = (bf16_t*)ws; ws += (size_t)MROWS * DIM * 2;
    bf16_t* Kb  = (bf16_t*)ws; ws += (size_t)MROWS * KVD * 2;
    bf16_t* Vb  = (bf16_t*)ws; ws += (size_t)MROWS * KVD * 2;
    bf16_t* Ob  = (bf16_t*)ws; ws += (size_t)MROWS * DIM * 2;

    const float qscale = 0.08838834764831845f;   // 1/sqrt(128)

    cvt_f32_bf16<<<(MROWS * DIM) / 1024, 256, 0, stream>>>(x, xb, MROWS * DIM);
    transpose_cvt<<<dim3(DIM / 32, DIM / 32), 256, 0, stream>>>(Wq, WqT, DIM, DIM);
    transpose_cvt<<<dim3(KVD / 32, DIM / 32), 256, 0, stream>>>(Wk, WkT, DIM, KVD);
    transpose_cvt<<<dim3(KVD / 32, DIM / 32), 256, 0, stream>>>(Wv, WvT, DIM, KVD);
    transpose_cvt<<<dim3(DIM / 32, DIM / 32), 256, 0, stream>>>(Wo, WoT, DIM, DIM);

    gemm_bt<bf16_t><<<dim3(DIM / 128, MROWS / 128), 256, 0, stream>>>(
        xb, WqT, bq, Qb, MROWS, DIM, DIM, qscale);
    gemm_bt<bf16_t><<<dim3(KVD / 128, MROWS / 128), 256, 0, stream>>>(
        xb, WkT, bk, Kb, MROWS, KVD, DIM, 1.0f);
    gemm_bt<bf16_t><<<dim3(KVD / 128, MROWS / 128), 256, 0, stream>>>(
        xb, WvT, bv, Vb, MROWS, KVD, DIM, 1.0f);

    attn_kernel<<<dim3(SEQ / 16, NHEAD, NB), 64, 0, stream>>>(Qb, Kb, Vb, Ob);

    gemm_bt<float><<<dim3(DIM / 128, MROWS / 128), 256, 0, stream>>>(
        Ob, WoT, bo, out, MROWS, DIM, DIM, 1.0f);
}

// Round 2
// 229.048 us; speedup vs baseline: 1.2566x; 1.2566x over previous
//
#include <hip/hip_runtime.h>
#include <hip/hip_bf16.h>
#include <math.h>

typedef __bf16 bf16_t;
typedef bf16_t bf16x8 __attribute__((ext_vector_type(8)));
typedef bf16_t bf16x4 __attribute__((ext_vector_type(4)));
typedef float  f32x4  __attribute__((ext_vector_type(4)));

#define NB    2
#define SEQ   2048
#define DIM   2048
#define NHEAD 16
#define NKVH  4
#define HDIM  128
#define WINSZ 256
#define KVD   512            // NKVH*HDIM
#define QKVN  3072           // DIM + 2*KVD
#define MROWS 4096           // NB*SEQ

// ---- async global->LDS, 16B per lane, dest = wave-uniform base + lane*16 ----
__device__ __forceinline__ void async_copy16(const void* g, void* lds) {
    __builtin_amdgcn_global_load_lds(
        (const __attribute__((address_space(1))) void*)g,
        (__attribute__((address_space(3))) void*)lds,
        16, 0, 0);
}

// ---- f32 -> bf16 elementwise (for x) ----
__global__ __launch_bounds__(256) void cvt_f32_bf16(const float* __restrict__ in,
                                                    bf16_t* __restrict__ out, int n) {
    int i = (blockIdx.x * 256 + threadIdx.x) * 4;
    if (i >= n) return;
    float4 v = *(const float4*)(in + i);
    bf16x4 o;
    o[0] = (bf16_t)v.x; o[1] = (bf16_t)v.y; o[2] = (bf16_t)v.z; o[3] = (bf16_t)v.w;
    *(bf16x4*)(out + i) = o;
}

// ---- W [K,N] f32  ->  W^T [N,K] bf16 ----
__global__ __launch_bounds__(256) void transpose_cvt(const float* __restrict__ in,
                                                     bf16_t* __restrict__ out, int K, int N) {
    __shared__ float tile[32][33];
    int tx = threadIdx.x & 31, ty = threadIdx.x >> 5;
    int n0 = blockIdx.x * 32, k0 = blockIdx.y * 32;
    for (int r = ty; r < 32; r += 8)
        tile[r][tx] = in[(size_t)(k0 + r) * N + n0 + tx];
    __syncthreads();
    for (int r = ty; r < 32; r += 8)
        out[(size_t)(n0 + r) * K + k0 + tx] = (bf16_t)tile[tx][r];
}

// ---- bqkv[3072] = concat(bq, bk, bv) ----
__global__ __launch_bounds__(256) void concat_bias(const float* __restrict__ bq,
                                                   const float* __restrict__ bk,
                                                   const float* __restrict__ bv,
                                                   float* __restrict__ out) {
    int i = blockIdx.x * 256 + threadIdx.x;
    if (i >= QKVN) return;
    float v = (i < DIM) ? bq[i] : ((i < DIM + KVD) ? bk[i - DIM] : bv[i - DIM - KVD]);
    out[i] = v;
}

// ---- V columns of QKVb -> Vt[b][g*128+d][j] (bf16 transpose) ----
__global__ __launch_bounds__(256) void transpose_v(const bf16_t* __restrict__ QKV,
                                                   bf16_t* __restrict__ Vt) {
    __shared__ bf16_t t[32][33];
    int tx = threadIdx.x & 31, ty = threadIdx.x >> 5;
    int j0 = blockIdx.x * 32, c0 = blockIdx.y * 32, b = blockIdx.z;
    for (int r = ty; r < 32; r += 8)
        t[r][tx] = QKV[((size_t)(b * SEQ) + j0 + r) * QKVN + (DIM + KVD) + c0 + tx];
    __syncthreads();
    for (int r = ty; r < 32; r += 8)
        Vt[((size_t)(b * KVD) + c0 + r) * SEQ + j0 + tx] = t[tx][r];
}

// ---- C[M,N] = (A[M,K] @ Bt[N,K]^T + bias); cols < qcols additionally * qs ----
template <typename OutT>
__global__ __launch_bounds__(256) void gemm_bt(const bf16_t* __restrict__ A,
                                               const bf16_t* __restrict__ Bt,
                                               const float* __restrict__ bias,
                                               OutT* __restrict__ C,
                                               int M, int N, int K, float qs, int qcols) {
    __shared__ bf16_t As[128 * 32];
    __shared__ bf16_t Bs[128 * 32];
    const int tid  = threadIdx.x;
    const int wave = tid >> 6;
    const int lane = tid & 63;
    const int lg = lane >> 4, lc = lane & 15;
    const int wr = wave >> 1, wc = wave & 1;
    const long brow = (long)blockIdx.y * 128;
    const long bcol = (long)blockIdx.x * 128;
    const int srow = lane >> 2;
    const int scol = (lane & 3) * 8;

    f32x4 acc[4][4] = {};

    for (int k0 = 0; k0 < K; k0 += 32) {
        __syncthreads();
#pragma unroll
        for (int q = 0; q < 2; ++q) {
            int chunk = wave * 2 + q;
            const bf16_t* ga = A  + (brow + chunk * 16 + srow) * (long)K + k0 + scol;
            const bf16_t* gb = Bt + (bcol + chunk * 16 + srow) * (long)K + k0 + scol;
            async_copy16(ga, As + chunk * 512);
            async_copy16(gb, Bs + chunk * 512);
        }
        __syncthreads();
        bf16x8 af[4], bfr[4];
#pragma unroll
        for (int m = 0; m < 4; ++m)
            af[m] = *(const bf16x8*)(As + (wr * 64 + m * 16 + lc) * 32 + lg * 8);
#pragma unroll
        for (int n = 0; n < 4; ++n)
            bfr[n] = *(const bf16x8*)(Bs + (wc * 64 + n * 16 + lc) * 32 + lg * 8);
#pragma unroll
        for (int m = 0; m < 4; ++m)
#pragma unroll
            for (int n = 0; n < 4; ++n)
                acc[m][n] = __builtin_amdgcn_mfma_f32_16x16x32_bf16(af[m], bfr[n], acc[m][n], 0, 0, 0);
    }

#pragma unroll
    for (int n = 0; n < 4; ++n) {
        int gc = (int)bcol + wc * 64 + n * 16 + lc;
        float bv = bias[gc];
        bool doscale = gc < qcols;
#pragma unroll
        for (int m = 0; m < 4; ++m) {
            long gr = brow + wr * 64 + m * 16 + 4 * lg;
#pragma unroll
            for (int r = 0; r < 4; ++r) {
                float v = acc[m][n][r] + bv;
                if (doscale) v *= qs;
                C[(gr + r) * N + gc] = (OutT)v;
            }
        }
    }
}

// ---- sliding-window GQA flash attention, 4 waves/block, no LDS barriers ----
__global__ __launch_bounds__(256) void attn_kernel(const bf16_t* __restrict__ QKV,
                                                   const bf16_t* __restrict__ Vt,
                                                   bf16_t* __restrict__ Ob) {
    __shared__ bf16_t Pls[4][32 * 18];   // per-wave P^T region, stride 18 (bank-spread)
    const int wv   = threadIdx.x >> 6;
    const int lane = threadIdx.x & 63;
    const int lg = lane >> 4, lc = lane & 15;
    const int wid = blockIdx.x * 4 + wv;
    const int ti = wid & 127;            // q-tile: fastest -> block's 4 waves share window
    const int h  = (wid >> 7) & 15;
    const int b  = wid >> 11;
    const int g  = h >> 2;
    const int i0 = ti * 16;
    const int irow = i0 + lc;
    bf16_t* P = Pls[wv];

    // Q fragments (scale 1/sqrt(HD)*log2(e) already folded in by the QKV GEMM)
    bf16x8 qf[4];
    {
        const bf16_t* qp = QKV + ((size_t)(b * SEQ) + irow) * QKVN + h * HDIM + lg * 8;
#pragma unroll
        for (int kk = 0; kk < 4; ++kk) qf[kk] = *(const bf16x8*)(qp + kk * 32);
    }
    const bf16_t* kb = QKV + (size_t)(b * SEQ) * QKVN + DIM + g * HDIM + lg * 8;
    const bf16_t* vb = Vt + ((size_t)(b * KVD) + g * HDIM + lc) * SEQ + lg * 8;

    float m_run = -1e30f, l_run = 0.f;
    f32x4 oacc[8] = {};   // O^T frags: d = c*16 + 4*lg + r, q = lc

    int jlo = i0 - (WINSZ - 1); if (jlo < 0) jlo = 0;
    const int jb_hi = (i0 + 15) >> 5;
    for (int jb = jlo >> 5; jb <= jb_hi; ++jb) {
        const int j0 = jb * 32;
        // S^T = K . Q^T  (two 16-j subtiles)
        f32x4 s[2];
#pragma unroll
        for (int t = 0; t < 2; ++t) {
            const bf16_t* kp = kb + (size_t)(j0 + t * 16 + lc) * QKVN;
            f32x4 sv = {};
#pragma unroll
            for (int kk = 0; kk < 4; ++kk) {
                bf16x8 kf = *(const bf16x8*)(kp + kk * 32);
                sv = __builtin_amdgcn_mfma_f32_16x16x32_bf16(kf, qf[kk], sv, 0, 0, 0);
            }
            s[t] = sv;
        }
        // prefetch V^T fragments (global, L2-resident) -- cover softmax latency
        bf16x8 vf[8];
#pragma unroll
        for (int c = 0; c < 8; ++c)
            vf[c] = *(const bf16x8*)(vb + (size_t)(c * 16) * SEQ + j0);

        const bool edge = (j0 < i0 - 240) || (j0 > i0 - 31);
        if (edge) {
#pragma unroll
            for (int t = 0; t < 2; ++t)
#pragma unroll
                for (int r = 0; r < 4; ++r) {
                    int j = j0 + t * 16 + 4 * lg + r;
                    if (j > irow || j < irow - (WINSZ - 1)) s[t][r] = -1e30f;
                }
        }
        float tmax = fmaxf(fmaxf(fmaxf(s[0][0], s[0][1]), fmaxf(s[0][2], s[0][3])),
                           fmaxf(fmaxf(s[1][0], s[1][1]), fmaxf(s[1][2], s[1][3])));
        tmax = fmaxf(tmax, __shfl_xor(tmax, 16, 64));
        tmax = fmaxf(tmax, __shfl_xor(tmax, 32, 64));
        // T13 defer-max: only rescale when some lane grew by > 8 (log2 units)
        if (!__all(tmax - m_run <= 8.0f)) {
            float m_new = fmaxf(m_run, tmax);
            float resc = __builtin_amdgcn_exp2f(m_run - m_new);
            l_run *= resc;
#pragma unroll
            for (int c = 0; c < 8; ++c) {
                oacc[c][0] *= resc; oacc[c][1] *= resc;
                oacc[c][2] *= resc; oacc[c][3] *= resc;
            }
            m_run = m_new;
        }
        float psum = 0.f;
        if (edge) {
#pragma unroll
            for (int t = 0; t < 2; ++t)
#pragma unroll
                for (int r = 0; r < 4; ++r) {
                    float sv = s[t][r];
                    float p = (sv < -5e29f) ? 0.f : __builtin_amdgcn_exp2f(sv - m_run);
                    psum += p;
                    P[(t * 16 + 4 * lg + r) * 18 + lc] = (bf16_t)p;
                }
        } else {
#pragma unroll
            for (int t = 0; t < 2; ++t)
#pragma unroll
                for (int r = 0; r < 4; ++r) {
                    float p = __builtin_amdgcn_exp2f(s[t][r] - m_run);
                    psum += p;
                    P[(t * 16 + 4 * lg + r) * 18 + lc] = (bf16_t)p;
                }
        }
        psum += __shfl_xor(psum, 16, 64);
        psum += __shfl_xor(psum, 32, 64);
        l_run += psum;
        // PV: O^T += V^T . P^T
        bf16x8 pf;
#pragma unroll
        for (int e = 0; e < 8; ++e) pf[e] = P[(lg * 8 + e) * 18 + lc];
#pragma unroll
        for (int c = 0; c < 8; ++c)
            oacc[c] = __builtin_amdgcn_mfma_f32_16x16x32_bf16(vf[c], pf, oacc[c], 0, 0, 0);
    }

    const float inv = 1.f / l_run;
#pragma unroll
    for (int c = 0; c < 8; ++c) {
        bf16x4 ov;
#pragma unroll
        for (int r = 0; r < 4; ++r) ov[r] = (bf16_t)(oacc[c][r] * inv);
        *(bf16x4*)(Ob + ((size_t)(b * SEQ) + irow) * DIM + h * HDIM + c * 16 + lg * 4) = ov;
    }
}

extern "C" void kernel_launch(void* const* d_in, const int* in_sizes, int n_in,
                              void* d_out, int out_size, void* d_ws, size_t ws_size,
                              hipStream_t stream) {
    const float* x  = (const float*)d_in[0];
    const float* Wq = (const float*)d_in[1];
    const float* bq = (const float*)d_in[2];
    const float* Wk = (const float*)d_in[3];
    const float* bk = (const float*)d_in[4];
    const float* Wv = (const float*)d_in[5];
    const float* bv = (const float*)d_in[6];
    const float* Wo = (const float*)d_in[7];
    const float* bo = (const float*)d_in[8];
    float* out = (float*)d_out;

    char* ws = (char*)d_ws;
    bf16_t* xb    = (bf16_t*)(ws);                       // 16 MB  (later aliased as Ob)
    bf16_t* WqkvT = (bf16_t*)(ws + (16u << 20));         // 12 MB  (later aliased as Vt)
    bf16_t* WoT   = (bf16_t*)(ws + (28u << 20));         //  8 MB
    bf16_t* QKVb  = (bf16_t*)(ws + (36u << 20));         // 24 MB
    float*  bqkv  = (float*) (ws + (60u << 20));         // 12 KB
    bf16_t* Vt    = WqkvT;   // weights dead after QKV GEMM
    bf16_t* Ob    = xb;      // x dead after QKV GEMM

    const float qs = 0.12751707498038074f;   // 1/sqrt(128) * log2(e)

    cvt_f32_bf16<<<(MROWS * DIM) / 1024, 256, 0, stream>>>(x, xb, MROWS * DIM);
    transpose_cvt<<<dim3(DIM / 32, DIM / 32), 256, 0, stream>>>(Wq, WqkvT, DIM, DIM);
    transpose_cvt<<<dim3(KVD / 32, DIM / 32), 256, 0, stream>>>(Wk, WqkvT + (size_t)DIM * DIM, DIM, KVD);
    transpose_cvt<<<dim3(KVD / 32, DIM / 32), 256, 0, stream>>>(Wv, WqkvT + (size_t)(DIM + KVD) * DIM, DIM, KVD);
    transpose_cvt<<<dim3(DIM / 32, DIM / 32), 256, 0, stream>>>(Wo, WoT, DIM, DIM);
    concat_bias<<<(QKVN + 255) / 256, 256, 0, stream>>>(bq, bk, bv, bqkv);

    // fused QKV projection: [4096,2048] x [2048,3072]; Q columns get qs folded in
    gemm_bt<bf16_t><<<dim3(QKVN / 128, MROWS / 128), 256, 0, stream>>>(
        xb, WqkvT, bqkv, QKVb, MROWS, QKVN, DIM, qs, DIM);

    transpose_v<<<dim3(SEQ / 32, KVD / 32, NB), 256, 0, stream>>>(QKVb, Vt);

    attn_kernel<<<dim3(MROWS * NHEAD / 16 / 4), 256, 0, stream>>>(QKVb, Vt, Ob);

    gemm_bt<float><<<dim3(DIM / 128, MROWS / 128), 256, 0, stream>>>(
        Ob, WoT, bo, out, MROWS, DIM, DIM, 1.0f, 0);
}

// Round 3
// 200.288 us; speedup vs baseline: 1.4370x; 1.1436x over previous
//
#include <hip/hip_runtime.h>
#include <hip/hip_bf16.h>
#include <math.h>

typedef __bf16 bf16_t;
typedef bf16_t bf16x8 __attribute__((ext_vector_type(8)));
typedef bf16_t bf16x4 __attribute__((ext_vector_type(4)));
typedef float  f32x4  __attribute__((ext_vector_type(4)));

#define NB    2
#define SEQ   2048
#define DIM   2048
#define NHEAD 16
#define NKVH  4
#define HDIM  128
#define WINSZ 256
#define KVD   512            // NKVH*HDIM
#define QKVN  3072           // DIM + 2*KVD
#define MROWS 4096           // NB*SEQ

// ---- async global->LDS, 16B per lane, dest = wave-uniform base + lane*16 ----
__device__ __forceinline__ void async_copy16(const void* g, void* lds) {
    __builtin_amdgcn_global_load_lds(
        (const __attribute__((address_space(1))) void*)g,
        (__attribute__((address_space(3))) void*)lds,
        16, 0, 0);
}

// ---- f32 -> bf16 elementwise (for x) ----
__global__ __launch_bounds__(256) void cvt_f32_bf16(const float* __restrict__ in,
                                                    bf16_t* __restrict__ out, int n) {
    int i = (blockIdx.x * 256 + threadIdx.x) * 4;
    if (i >= n) return;
    float4 v = *(const float4*)(in + i);
    bf16x4 o;
    o[0] = (bf16_t)v.x; o[1] = (bf16_t)v.y; o[2] = (bf16_t)v.z; o[3] = (bf16_t)v.w;
    *(bf16x4*)(out + i) = o;
}

// ---- W [K,N] f32  ->  W^T [N,K] bf16 ----
__global__ __launch_bounds__(256) void transpose_cvt(const float* __restrict__ in,
                                                     bf16_t* __restrict__ out, int K, int N) {
    __shared__ float tile[32][33];
    int tx = threadIdx.x & 31, ty = threadIdx.x >> 5;
    int n0 = blockIdx.x * 32, k0 = blockIdx.y * 32;
    for (int r = ty; r < 32; r += 8)
        tile[r][tx] = in[(size_t)(k0 + r) * N + n0 + tx];
    __syncthreads();
    for (int r = ty; r < 32; r += 8)
        out[(size_t)(n0 + r) * K + k0 + tx] = (bf16_t)tile[tx][r];
}

// ---- bqkv[3072] = concat(bq, bk, bv) ----
__global__ __launch_bounds__(256) void concat_bias(const float* __restrict__ bq,
                                                   const float* __restrict__ bk,
                                                   const float* __restrict__ bv,
                                                   float* __restrict__ out) {
    int i = blockIdx.x * 256 + threadIdx.x;
    if (i >= QKVN) return;
    float v = (i < DIM) ? bq[i] : ((i < DIM + KVD) ? bk[i - DIM] : bv[i - DIM - KVD]);
    out[i] = v;
}

// ---- V columns of QKVb -> Vt[b][g*128+d][j] (bf16 transpose) ----
__global__ __launch_bounds__(256) void transpose_v(const bf16_t* __restrict__ QKV,
                                                   bf16_t* __restrict__ Vt) {
    __shared__ bf16_t t[32][33];
    int tx = threadIdx.x & 31, ty = threadIdx.x >> 5;
    int j0 = blockIdx.x * 32, c0 = blockIdx.y * 32, b = blockIdx.z;
    for (int r = ty; r < 32; r += 8)
        t[r][tx] = QKV[((size_t)(b * SEQ) + j0 + r) * QKVN + (DIM + KVD) + c0 + tx];
    __syncthreads();
    for (int r = ty; r < 32; r += 8)
        Vt[((size_t)(b * KVD) + c0 + r) * SEQ + j0 + tx] = t[tx][r];
}

// ============================================================================
// Pipelined 2-phase-per-K-tile GEMM (T3/T4/T2/T5).  C = A[M,K] @ Bt[N,K]^T.
// Geometry: BMxBN tile, BK=64 split into two K=32 halves; 8 waves (2x4),
// per-wave C = (BM/2) x 64.  LDS: 2 buffers x {A half0, A half1, B half0,
// B half1}; halves are consumed strictly sequentially (phase p reads only
// half p), so staging K-tile t+1's half p during phase (t,p) targets a
// region whose last readers finished two barriers earlier -> race-free with
// ONE barrier per phase.  Counted vmcnt(ISS) keeps exactly one phase of
// global_load_lds in flight across barriers (vmcnt(0) only at last phase).
// LDS XOR-swizzle: 16B chunk c of row r holds source chunk c ^ ((r>>1)&3);
// applied inversely on the global source (global_load_lds dest stays linear)
// and identically on ds_read -> 2-way banks (free) instead of 8-way.
// ============================================================================
template <int BM, int BN, typename OutT>
__global__ __launch_bounds__(512, 1) void gemm8p(const bf16_t* __restrict__ A,
                                                 const bf16_t* __restrict__ Bt,
                                                 const float* __restrict__ bias,
                                                 OutT* __restrict__ C,
                                                 int M, int N, int K, float qs, int qcols) {
    constexpr int AISS = BM / 128;          // global_load_lds issues per A half
    constexpr int BISS = BN / 128;
    constexpr int ISS  = AISS + BISS;       // stage issues per phase
    constexpr int MF   = BM / 32;           // 16x16 frags per wave, M dir
    constexpr int NF   = BN / 64;           // frags per wave, N dir
    constexpr int AHALF = BM * 32;          // elems per A K-half
    constexpr int BHALF = BN * 32;
    constexpr int BUFSZ = 2 * (AHALF + BHALF);
    __shared__ bf16_t lds[2 * BUFSZ];

    const int tid  = threadIdx.x;
    const int wave = tid >> 6;
    const int lane = tid & 63;
    const int lg = lane >> 4, lc = lane & 15;
    const int wr = wave >> 2, wc = wave & 3;

    // XCD-aware block swizzle (nblk % 8 == 0 for all our grids)
    const int nbn  = N / BN;
    const int nblk = (M / BM) * nbn;
    const int qq   = nblk >> 3;
    const int swz  = (blockIdx.x & 7) * qq + (blockIdx.x >> 3);
    const long brow = (long)(swz / nbn) * BM;
    const long bcol = (long)(swz % nbn) * BN;

    const int srow   = tid >> 2;
    const int schunk = (tid & 3) ^ ((tid >> 3) & 3);   // inverse swizzle on source

    f32x4 acc[MF][NF] = {};

    auto stage = [&](int buf, int p, int kt) {
        const int kcol = kt * 64 + p * 32 + schunk * 8;
        const bf16_t* gA = A + (brow + srow) * (long)K + kcol;
        bf16_t* dA = lds + buf * BUFSZ + p * AHALF + tid * 8;
#pragma unroll
        for (int i = 0; i < AISS; ++i)
            async_copy16(gA + (long)i * 128 * K, dA + i * 4096);
        const bf16_t* gB = Bt + (bcol + srow) * (long)K + kcol;
        bf16_t* dB = lds + buf * BUFSZ + 2 * AHALF + p * BHALF + tid * 8;
#pragma unroll
        for (int i = 0; i < BISS; ++i)
            async_copy16(gB + (long)i * 128 * K, dB + i * 4096);
    };

    stage(0, 0, 0);
    stage(0, 1, 0);

    const int NT = K >> 6;
    const int cswz = (lg ^ ((lc >> 1) & 3)) * 8;
    for (int t = 0; t < NT; ++t) {
#pragma unroll
        for (int p = 0; p < 2; ++p) {
            if (t == NT - 1 && p == 1) {
                asm volatile("s_waitcnt vmcnt(0)" ::: "memory");
            } else if constexpr (ISS == 4) {
                asm volatile("s_waitcnt vmcnt(4)" ::: "memory");
            } else {
                asm volatile("s_waitcnt vmcnt(3)" ::: "memory");
            }
            __builtin_amdgcn_s_barrier();
            asm volatile("" ::: "memory");   // no LDS read hoists above barrier
            const bf16_t* Ab = lds + (t & 1) * BUFSZ + p * AHALF;
            const bf16_t* Bb = lds + (t & 1) * BUFSZ + 2 * AHALF + p * BHALF;
            bf16x8 af[MF], bv[NF];
#pragma unroll
            for (int m = 0; m < MF; ++m)
                af[m] = *(const bf16x8*)(Ab + (wr * (BM / 2) + m * 16 + lc) * 32 + cswz);
#pragma unroll
            for (int n = 0; n < NF; ++n)
                bv[n] = *(const bf16x8*)(Bb + (wc * 64 + n * 16 + lc) * 32 + cswz);
            if (t + 1 < NT) stage((t + 1) & 1, p, t + 1);
            asm volatile("s_waitcnt lgkmcnt(0)" ::: "memory");
            __builtin_amdgcn_sched_barrier(0);
            __builtin_amdgcn_s_setprio(1);
#pragma unroll
            for (int m = 0; m < MF; ++m)
#pragma unroll
                for (int n = 0; n < NF; ++n)
                    acc[m][n] = __builtin_amdgcn_mfma_f32_16x16x32_bf16(af[m], bv[n], acc[m][n], 0, 0, 0);
            __builtin_amdgcn_s_setprio(0);
        }
    }

#pragma unroll
    for (int n = 0; n < NF; ++n) {
        int gc = (int)bcol + wc * 64 + n * 16 + lc;
        float bvs = bias[gc];
        bool ds = gc < qcols;
#pragma unroll
        for (int m = 0; m < MF; ++m) {
            long gr = brow + wr * (BM / 2) + m * 16 + 4 * lg;
#pragma unroll
            for (int r = 0; r < 4; ++r) {
                float v = acc[m][n][r] + bvs;
                if (ds) v *= qs;
                C[(gr + r) * (long)N + gc] = (OutT)v;
            }
        }
    }
}

// ---- sliding-window GQA flash attention, 4 waves/block, no LDS barriers ----
__global__ __launch_bounds__(256) void attn_kernel(const bf16_t* __restrict__ QKV,
                                                   const bf16_t* __restrict__ Vt,
                                                   bf16_t* __restrict__ Ob) {
    __shared__ bf16_t Pls[4][32 * 18];   // per-wave P^T region, stride 18 (bank-spread)
    const int wv   = threadIdx.x >> 6;
    const int lane = threadIdx.x & 63;
    const int lg = lane >> 4, lc = lane & 15;
    const int wid = blockIdx.x * 4 + wv;
    const int ti = wid & 127;            // q-tile: fastest -> block's 4 waves share window
    const int h  = (wid >> 7) & 15;
    const int b  = wid >> 11;
    const int g  = h >> 2;
    const int i0 = ti * 16;
    const int irow = i0 + lc;
    bf16_t* P = Pls[wv];

    bf16x8 qf[4];
    {
        const bf16_t* qp = QKV + ((size_t)(b * SEQ) + irow) * QKVN + h * HDIM + lg * 8;
#pragma unroll
        for (int kk = 0; kk < 4; ++kk) qf[kk] = *(const bf16x8*)(qp + kk * 32);
    }
    const bf16_t* kb = QKV + (size_t)(b * SEQ) * QKVN + DIM + g * HDIM + lg * 8;
    const bf16_t* vb = Vt + ((size_t)(b * KVD) + g * HDIM + lc) * SEQ + lg * 8;

    float m_run = -1e30f, l_run = 0.f;
    f32x4 oacc[8] = {};

    int jlo = i0 - (WINSZ - 1); if (jlo < 0) jlo = 0;
    const int jb_hi = (i0 + 15) >> 5;
    for (int jb = jlo >> 5; jb <= jb_hi; ++jb) {
        const int j0 = jb * 32;
        f32x4 s[2];
#pragma unroll
        for (int t = 0; t < 2; ++t) {
            const bf16_t* kp = kb + (size_t)(j0 + t * 16 + lc) * QKVN;
            f32x4 sv = {};
#pragma unroll
            for (int kk = 0; kk < 4; ++kk) {
                bf16x8 kf = *(const bf16x8*)(kp + kk * 32);
                sv = __builtin_amdgcn_mfma_f32_16x16x32_bf16(kf, qf[kk], sv, 0, 0, 0);
            }
            s[t] = sv;
        }
        bf16x8 vf[8];
#pragma unroll
        for (int c = 0; c < 8; ++c)
            vf[c] = *(const bf16x8*)(vb + (size_t)(c * 16) * SEQ + j0);

        const bool edge = (j0 < i0 - 240) || (j0 > i0 - 31);
        if (edge) {
#pragma unroll
            for (int t = 0; t < 2; ++t)
#pragma unroll
                for (int r = 0; r < 4; ++r) {
                    int j = j0 + t * 16 + 4 * lg + r;
                    if (j > irow || j < irow - (WINSZ - 1)) s[t][r] = -1e30f;
                }
        }
        float tmax = fmaxf(fmaxf(fmaxf(s[0][0], s[0][1]), fmaxf(s[0][2], s[0][3])),
                           fmaxf(fmaxf(s[1][0], s[1][1]), fmaxf(s[1][2], s[1][3])));
        tmax = fmaxf(tmax, __shfl_xor(tmax, 16, 64));
        tmax = fmaxf(tmax, __shfl_xor(tmax, 32, 64));
        if (!__all(tmax - m_run <= 8.0f)) {
            float m_new = fmaxf(m_run, tmax);
            float resc = __builtin_amdgcn_exp2f(m_run - m_new);
            l_run *= resc;
#pragma unroll
            for (int c = 0; c < 8; ++c) {
                oacc[c][0] *= resc; oacc[c][1] *= resc;
                oacc[c][2] *= resc; oacc[c][3] *= resc;
            }
            m_run = m_new;
        }
        float psum = 0.f;
        if (edge) {
#pragma unroll
            for (int t = 0; t < 2; ++t)
#pragma unroll
                for (int r = 0; r < 4; ++r) {
                    float sv = s[t][r];
                    float p = (sv < -5e29f) ? 0.f : __builtin_amdgcn_exp2f(sv - m_run);
                    psum += p;
                    P[(t * 16 + 4 * lg + r) * 18 + lc] = (bf16_t)p;
                }
        } else {
#pragma unroll
            for (int t = 0; t < 2; ++t)
#pragma unroll
                for (int r = 0; r < 4; ++r) {
                    float p = __builtin_amdgcn_exp2f(s[t][r] - m_run);
                    psum += p;
                    P[(t * 16 + 4 * lg + r) * 18 + lc] = (bf16_t)p;
                }
        }
        psum += __shfl_xor(psum, 16, 64);
        psum += __shfl_xor(psum, 32, 64);
        l_run += psum;
        bf16x8 pf;
#pragma unroll
        for (int e = 0; e < 8; ++e) pf[e] = P[(lg * 8 + e) * 18 + lc];
#pragma unroll
        for (int c = 0; c < 8; ++c)
            oacc[c] = __builtin_amdgcn_mfma_f32_16x16x32_bf16(vf[c], pf, oacc[c], 0, 0, 0);
    }

    const float inv = 1.f / l_run;
#pragma unroll
    for (int c = 0; c < 8; ++c) {
        bf16x4 ov;
#pragma unroll
        for (int r = 0; r < 4; ++r) ov[r] = (bf16_t)(oacc[c][r] * inv);
        *(bf16x4*)(Ob + ((size_t)(b * SEQ) + irow) * DIM + h * HDIM + c * 16 + lg * 4) = ov;
    }
}

extern "C" void kernel_launch(void* const* d_in, const int* in_sizes, int n_in,
                              void* d_out, int out_size, void* d_ws, size_t ws_size,
                              hipStream_t stream) {
    const float* x  = (const float*)d_in[0];
    const float* Wq = (const float*)d_in[1];
    const float* bq = (const float*)d_in[2];
    const float* Wk = (const float*)d_in[3];
    const float* bk = (const float*)d_in[4];
    const float* Wv = (const float*)d_in[5];
    const float* bv = (const float*)d_in[6];
    const float* Wo = (const float*)d_in[7];
    const float* bo = (const float*)d_in[8];
    float* out = (float*)d_out;

    char* ws = (char*)d_ws;
    bf16_t* xb    = (bf16_t*)(ws);                       // 16 MB  (later aliased as Ob)
    bf16_t* WqkvT = (bf16_t*)(ws + (16u << 20));         // 12 MB  (later aliased as Vt)
    bf16_t* WoT   = (bf16_t*)(ws + (28u << 20));         //  8 MB
    bf16_t* QKVb  = (bf16_t*)(ws + (36u << 20));         // 24 MB
    float*  bqkv  = (float*) (ws + (60u << 20));         // 12 KB
    bf16_t* Vt    = WqkvT;   // weights dead after QKV GEMM
    bf16_t* Ob    = xb;      // x dead after QKV GEMM

    const float qs = 0.12751707498038074f;   // 1/sqrt(128) * log2(e)

    cvt_f32_bf16<<<(MROWS * DIM) / 1024, 256, 0, stream>>>(x, xb, MROWS * DIM);
    transpose_cvt<<<dim3(DIM / 32, DIM / 32), 256, 0, stream>>>(Wq, WqkvT, DIM, DIM);
    transpose_cvt<<<dim3(KVD / 32, DIM / 32), 256, 0, stream>>>(Wk, WqkvT + (size_t)DIM * DIM, DIM, KVD);
    transpose_cvt<<<dim3(KVD / 32, DIM / 32), 256, 0, stream>>>(Wv, WqkvT + (size_t)(DIM + KVD) * DIM, DIM, KVD);
    transpose_cvt<<<dim3(DIM / 32, DIM / 32), 256, 0, stream>>>(Wo, WoT, DIM, DIM);
    concat_bias<<<(QKVN + 255) / 256, 256, 0, stream>>>(bq, bk, bv, bqkv);

    // fused QKV projection: [4096,2048] x [2048,3072]; Q columns get qs folded in
    gemm8p<256, 256, bf16_t><<<dim3((MROWS / 256) * (QKVN / 256)), 512, 0, stream>>>(
        xb, WqkvT, bqkv, QKVb, MROWS, QKVN, DIM, qs, DIM);

    transpose_v<<<dim3(SEQ / 32, KVD / 32, NB), 256, 0, stream>>>(QKVb, Vt);

    attn_kernel<<<dim3(MROWS * NHEAD / 16 / 4), 256, 0, stream>>>(QKVb, Vt, Ob);

    // output projection: [4096,2048] x [2048,2048] -> f32; BM=128 fills all 256 CUs
    gemm8p<128, 256, float><<<dim3((MROWS / 128) * (DIM / 256)), 512, 0, stream>>>(
        Ob, WoT, bo, out, MROWS, DIM, DIM, 1.0f, 0);
}

// Round 4
// 159.927 us; speedup vs baseline: 1.7996x; 1.2524x over previous
//
#include <hip/hip_runtime.h>
#include <hip/hip_bf16.h>
#include <math.h>

typedef __bf16 bf16_t;
typedef bf16_t bf16x8 __attribute__((ext_vector_type(8)));
typedef bf16_t bf16x4 __attribute__((ext_vector_type(4)));
typedef float  f32x4  __attribute__((ext_vector_type(4)));

#define NB    2
#define SEQ   2048
#define DIM   2048
#define NHEAD 16
#define NKVH  4
#define HDIM  128
#define WINSZ 256
#define KVD   512            // NKVH*HDIM
#define QKVN  3072           // DIM + 2*KVD
#define MROWS 4096           // NB*SEQ

// ---- async global->LDS, 16B per lane, dest = wave-uniform base + lane*16 ----
__device__ __forceinline__ void async_copy16(const void* g, void* lds) {
    __builtin_amdgcn_global_load_lds(
        (const __attribute__((address_space(1))) void*)g,
        (__attribute__((address_space(3))) void*)lds,
        16, 0, 0);
}

// ---- f32 -> bf16 elementwise (for x) ----
__global__ __launch_bounds__(256) void cvt_f32_bf16(const float* __restrict__ in,
                                                    bf16_t* __restrict__ out, int n) {
    int i = (blockIdx.x * 256 + threadIdx.x) * 4;
    if (i >= n) return;
    float4 v = *(const float4*)(in + i);
    bf16x4 o;
    o[0] = (bf16_t)v.x; o[1] = (bf16_t)v.y; o[2] = (bf16_t)v.z; o[3] = (bf16_t)v.w;
    *(bf16x4*)(out + i) = o;
}

// ---- W [K,N] f32  ->  W^T [N,K] bf16 ----
__global__ __launch_bounds__(256) void transpose_cvt(const float* __restrict__ in,
                                                     bf16_t* __restrict__ out, int K, int N) {
    __shared__ float tile[32][33];
    int tx = threadIdx.x & 31, ty = threadIdx.x >> 5;
    int n0 = blockIdx.x * 32, k0 = blockIdx.y * 32;
    for (int r = ty; r < 32; r += 8)
        tile[r][tx] = in[(size_t)(k0 + r) * N + n0 + tx];
    __syncthreads();
    for (int r = ty; r < 32; r += 8)
        out[(size_t)(n0 + r) * K + k0 + tx] = (bf16_t)tile[tx][r];
}

// ---- bqkv[3072] = concat(bq, bk, bv) ----
__global__ __launch_bounds__(256) void concat_bias(const float* __restrict__ bq,
                                                   const float* __restrict__ bk,
                                                   const float* __restrict__ bv,
                                                   float* __restrict__ out) {
    int i = blockIdx.x * 256 + threadIdx.x;
    if (i >= QKVN) return;
    float v = (i < DIM) ? bq[i] : ((i < DIM + KVD) ? bk[i - DIM] : bv[i - DIM - KVD]);
    out[i] = v;
}

// ---- V columns of QKVb -> blocked V^T tiles: Vtb[(b*4+g)*64+jb][128 d][32 j] ----
// Each 128x32 tile is a CONTIGUOUS 8KB block -> attn stages it with fully
// coalesced global_load_lds.
__global__ __launch_bounds__(256) void transpose_v(const bf16_t* __restrict__ QKV,
                                                   bf16_t* __restrict__ Vtb) {
    __shared__ bf16_t t[32][33];
    int tx = threadIdx.x & 31, ty = threadIdx.x >> 5;
    int jb = blockIdx.x, c0 = blockIdx.y * 32, b = blockIdx.z;
    int j0 = jb * 32;
    for (int r = ty; r < 32; r += 8)
        t[r][tx] = QKV[((size_t)(b * SEQ) + j0 + r) * QKVN + (DIM + KVD) + c0 + tx];
    __syncthreads();
    int g = c0 >> 7, dl = c0 & 127;
    bf16_t* outb = Vtb + (((size_t)(b * NKVH) + g) * 64 + jb) * 4096;
    for (int r = ty; r < 32; r += 8)
        outb[(dl + r) * 32 + tx] = t[tx][r];
}

// ============================================================================
// Pipelined 2-phase-per-K-tile GEMM (T3/T4/T2/T5).  C = A[M,K] @ Bt[N,K]^T.
// ============================================================================
template <int BM, int BN, typename OutT>
__global__ __launch_bounds__(512, 1) void gemm8p(const bf16_t* __restrict__ A,
                                                 const bf16_t* __restrict__ Bt,
                                                 const float* __restrict__ bias,
                                                 OutT* __restrict__ C,
                                                 int M, int N, int K, float qs, int qcols) {
    constexpr int AISS = BM / 128;
    constexpr int BISS = BN / 128;
    constexpr int ISS  = AISS + BISS;
    constexpr int MF   = BM / 32;
    constexpr int NF   = BN / 64;
    constexpr int AHALF = BM * 32;
    constexpr int BHALF = BN * 32;
    constexpr int BUFSZ = 2 * (AHALF + BHALF);
    __shared__ bf16_t lds[2 * BUFSZ];

    const int tid  = threadIdx.x;
    const int wave = tid >> 6;
    const int lane = tid & 63;
    const int lg = lane >> 4, lc = lane & 15;
    const int wr = wave >> 2, wc = wave & 3;

    const int nbn  = N / BN;
    const int nblk = (M / BM) * nbn;
    const int qq   = nblk >> 3;
    const int swz  = (blockIdx.x & 7) * qq + (blockIdx.x >> 3);
    const long brow = (long)(swz / nbn) * BM;
    const long bcol = (long)(swz % nbn) * BN;

    const int srow   = tid >> 2;
    const int schunk = (tid & 3) ^ ((tid >> 3) & 3);

    f32x4 acc[MF][NF] = {};

    auto stage = [&](int buf, int p, int kt) {
        const int kcol = kt * 64 + p * 32 + schunk * 8;
        const bf16_t* gA = A + (brow + srow) * (long)K + kcol;
        bf16_t* dA = lds + buf * BUFSZ + p * AHALF + tid * 8;
#pragma unroll
        for (int i = 0; i < AISS; ++i)
            async_copy16(gA + (long)i * 128 * K, dA + i * 4096);
        const bf16_t* gB = Bt + (bcol + srow) * (long)K + kcol;
        bf16_t* dB = lds + buf * BUFSZ + 2 * AHALF + p * BHALF + tid * 8;
#pragma unroll
        for (int i = 0; i < BISS; ++i)
            async_copy16(gB + (long)i * 128 * K, dB + i * 4096);
    };

    stage(0, 0, 0);
    stage(0, 1, 0);

    const int NT = K >> 6;
    const int cswz = (lg ^ ((lc >> 1) & 3)) * 8;
    for (int t = 0; t < NT; ++t) {
#pragma unroll
        for (int p = 0; p < 2; ++p) {
            if (t == NT - 1 && p == 1) {
                asm volatile("s_waitcnt vmcnt(0)" ::: "memory");
            } else if constexpr (ISS == 4) {
                asm volatile("s_waitcnt vmcnt(4)" ::: "memory");
            } else {
                asm volatile("s_waitcnt vmcnt(3)" ::: "memory");
            }
            __builtin_amdgcn_s_barrier();
            asm volatile("" ::: "memory");
            const bf16_t* Ab = lds + (t & 1) * BUFSZ + p * AHALF;
            const bf16_t* Bb = lds + (t & 1) * BUFSZ + 2 * AHALF + p * BHALF;
            bf16x8 af[MF], bv[NF];
#pragma unroll
            for (int m = 0; m < MF; ++m)
                af[m] = *(const bf16x8*)(Ab + (wr * (BM / 2) + m * 16 + lc) * 32 + cswz);
#pragma unroll
            for (int n = 0; n < NF; ++n)
                bv[n] = *(const bf16x8*)(Bb + (wc * 64 + n * 16 + lc) * 32 + cswz);
            if (t + 1 < NT) stage((t + 1) & 1, p, t + 1);
            asm volatile("s_waitcnt lgkmcnt(0)" ::: "memory");
            __builtin_amdgcn_sched_barrier(0);
            __builtin_amdgcn_s_setprio(1);
#pragma unroll
            for (int m = 0; m < MF; ++m)
#pragma unroll
                for (int n = 0; n < NF; ++n)
                    acc[m][n] = __builtin_amdgcn_mfma_f32_16x16x32_bf16(af[m], bv[n], acc[m][n], 0, 0, 0);
            __builtin_amdgcn_s_setprio(0);
        }
    }

#pragma unroll
    for (int n = 0; n < NF; ++n) {
        int gc = (int)bcol + wc * 64 + n * 16 + lc;
        float bvs = bias[gc];
        bool ds = gc < qcols;
#pragma unroll
        for (int m = 0; m < MF; ++m) {
            long gr = brow + wr * (BM / 2) + m * 16 + 4 * lg;
#pragma unroll
            for (int r = 0; r < 4; ++r) {
                float v = acc[m][n][r] + bvs;
                if (ds) v *= qs;
                C[(gr + r) * (long)N + gc] = (OutT)v;
            }
        }
    }
}

// ============================================================================
// Sliding-window GQA flash attention.  Block = 4 waves = the 4 heads of one
// KV group on one 16-row q-tile; K/V j-tiles staged ONCE per block into
// double-buffered LDS (coalesced global_load_lds, XOR-swizzled fragments),
// shared by all 4 waves.  One barrier per j-block; staging of j+1 overlaps
// compute of j (counted per-wave vmcnt: each wave issues its own 4 loads).
// ============================================================================
__global__ __launch_bounds__(256) void attn_kernel(const bf16_t* __restrict__ QKV,
                                                   const bf16_t* __restrict__ Vtb,
                                                   bf16_t* __restrict__ Ob) {
    __shared__ bf16_t Kls[2][32 * 128];   // [j][d], row 256B, chunk^=(row&7)
    __shared__ bf16_t Vls[2][128 * 32];   // [d][j], row 64B, chunk^=((row^(row>>2))&3)
    __shared__ bf16_t Pls[4][16 * 40];    // per-wave P [q][j], stride 40 elems

    const int wv   = threadIdx.x >> 6;
    const int lane = threadIdx.x & 63;
    const int lg = lane >> 4, lc = lane & 15;

    // bijective XCD swizzle: 1024 blocks -> 128 per XCD = exactly one (b,g)
    const int swb = (blockIdx.x & 7) * 128 + (blockIdx.x >> 3);
    const int ti = swb & 127;
    const int g  = (swb >> 7) & 3;
    const int b  = swb >> 9;
    const int h  = g * 4 + wv;
    const int i0 = ti * 16;
    const int irow = i0 + lc;
    bf16_t* P = &Pls[wv][0];

    // Q fragments (1/sqrt(128)*log2(e) folded in by the QKV GEMM)
    bf16x8 qf[4];
    {
        const bf16_t* qp = QKV + ((size_t)(b * SEQ) + irow) * QKVN + h * HDIM + lg * 8;
#pragma unroll
        for (int kk = 0; kk < 4; ++kk) qf[kk] = *(const bf16x8*)(qp + kk * 32);
    }

    auto stage = [&](int buf, int jb) {
        const int j0s = jb * 32;
        const bf16_t* kgb = QKV + ((size_t)(b * SEQ) + j0s) * QKVN + DIM + g * HDIM;
#pragma unroll
        for (int ii = 0; ii < 2; ++ii) {
            int i = wv * 2 + ii;
            int row = i * 4 + (lane >> 4);
            int ch  = (lane & 15) ^ (row & 7);
            async_copy16(kgb + (size_t)row * QKVN + ch * 8, &Kls[buf][i * 512]);
        }
        const bf16_t* vgb = Vtb + (((size_t)(b * NKVH) + g) * 64 + jb) * 4096;
#pragma unroll
        for (int ii = 0; ii < 2; ++ii) {
            int i = wv * 2 + ii;
            int row = i * 16 + (lane >> 2);
            int ch  = (lane & 3) ^ ((row ^ (row >> 2)) & 3);
            async_copy16(vgb + row * 32 + ch * 8, &Vls[buf][i * 512]);
        }
    };

    float m_run = -1e30f, l_run = 0.f;
    f32x4 oacc[8] = {};   // O^T frags: d = c*16 + 4*lg + r, q = lc

    int jlo = i0 - (WINSZ - 1); if (jlo < 0) jlo = 0;
    const int jb0 = jlo >> 5;
    const int jb1 = (i0 + 15) >> 5;

    stage(0, jb0);

    for (int jb = jb0; jb <= jb1; ++jb) {
        const int j0 = jb * 32;
        const int cur = (jb - jb0) & 1;
        asm volatile("s_waitcnt vmcnt(0)" ::: "memory");
        __builtin_amdgcn_s_barrier();
        asm volatile("" ::: "memory");

        // K fragments from LDS (swizzled b128, conflict-free)
        bf16x8 kf[2][4];
#pragma unroll
        for (int t = 0; t < 2; ++t)
#pragma unroll
            for (int kk = 0; kk < 4; ++kk) {
                int row = t * 16 + lc;
                int ch  = (kk * 4 + lg) ^ (row & 7);
                kf[t][kk] = *(const bf16x8*)(&Kls[cur][row * 128 + ch * 8]);
            }
        if (jb < jb1) stage(cur ^ 1, jb + 1);
        asm volatile("s_waitcnt lgkmcnt(0)" ::: "memory");
        __builtin_amdgcn_sched_barrier(0);

        // S^T = K . Q^T
        f32x4 s[2];
        __builtin_amdgcn_s_setprio(1);
#pragma unroll
        for (int t = 0; t < 2; ++t) {
            f32x4 sv = {};
#pragma unroll
            for (int kk = 0; kk < 4; ++kk)
                sv = __builtin_amdgcn_mfma_f32_16x16x32_bf16(kf[t][kk], qf[kk], sv, 0, 0, 0);
            s[t] = sv;
        }
        __builtin_amdgcn_s_setprio(0);

        const bool edge = (j0 < i0 - 240) || (j0 > i0 - 31);
        if (edge) {
#pragma unroll
            for (int t = 0; t < 2; ++t)
#pragma unroll
                for (int r = 0; r < 4; ++r) {
                    int j = j0 + t * 16 + 4 * lg + r;
                    if (j > irow || j < irow - (WINSZ - 1)) s[t][r] = -1e30f;
                }
        }
        float tmax = fmaxf(fmaxf(fmaxf(s[0][0], s[0][1]), fmaxf(s[0][2], s[0][3])),
                           fmaxf(fmaxf(s[1][0], s[1][1]), fmaxf(s[1][2], s[1][3])));
        tmax = fmaxf(tmax, __shfl_xor(tmax, 16, 64));
        tmax = fmaxf(tmax, __shfl_xor(tmax, 32, 64));
        if (!__all(tmax - m_run <= 8.0f)) {   // T13 defer-max
            float m_new = fmaxf(m_run, tmax);
            float resc = __builtin_amdgcn_exp2f(m_run - m_new);
            l_run *= resc;
#pragma unroll
            for (int c = 0; c < 8; ++c) {
                oacc[c][0] *= resc; oacc[c][1] *= resc;
                oacc[c][2] *= resc; oacc[c][3] *= resc;
            }
            m_run = m_new;
        }
        float psum = 0.f;
#pragma unroll
        for (int t = 0; t < 2; ++t) {
            bf16x4 pk;
#pragma unroll
            for (int r = 0; r < 4; ++r) {
                float sv = s[t][r];
                float p = (edge && sv < -5e29f) ? 0.f : __builtin_amdgcn_exp2f(sv - m_run);
                psum += p;
                pk[r] = (bf16_t)p;
            }
            *(bf16x4*)(P + lc * 40 + t * 16 + lg * 4) = pk;   // packed ds_write_b64
        }
        psum += __shfl_xor(psum, 16, 64);
        psum += __shfl_xor(psum, 32, 64);
        l_run += psum;
        asm volatile("" ::: "memory");   // keep P write before P read (same-wave DS order)

        // V^T fragments + P fragment (all LDS b128)
        bf16x8 vf[8];
#pragma unroll
        for (int c = 0; c < 8; ++c) {
            int row = c * 16 + lc;
            int ch  = lg ^ ((row ^ (row >> 2)) & 3);
            vf[c] = *(const bf16x8*)(&Vls[cur][row * 32 + ch * 8]);
        }
        bf16x8 pf = *(const bf16x8*)(P + lc * 40 + lg * 8);

        __builtin_amdgcn_s_setprio(1);
#pragma unroll
        for (int c = 0; c < 8; ++c)
            oacc[c] = __builtin_amdgcn_mfma_f32_16x16x32_bf16(vf[c], pf, oacc[c], 0, 0, 0);
        __builtin_amdgcn_s_setprio(0);
    }

    const float inv = 1.f / l_run;
#pragma unroll
    for (int c = 0; c < 8; ++c) {
        bf16x4 ov;
#pragma unroll
        for (int r = 0; r < 4; ++r) ov[r] = (bf16_t)(oacc[c][r] * inv);
        *(bf16x4*)(Ob + ((size_t)(b * SEQ) + irow) * DIM + h * HDIM + c * 16 + lg * 4) = ov;
    }
}

extern "C" void kernel_launch(void* const* d_in, const int* in_sizes, int n_in,
                              void* d_out, int out_size, void* d_ws, size_t ws_size,
                              hipStream_t stream) {
    const float* x  = (const float*)d_in[0];
    const float* Wq = (const float*)d_in[1];
    const float* bq = (const float*)d_in[2];
    const float* Wk = (const float*)d_in[3];
    const float* bk = (const float*)d_in[4];
    const float* Wv = (const float*)d_in[5];
    const float* bv = (const float*)d_in[6];
    const float* Wo = (const float*)d_in[7];
    const float* bo = (const float*)d_in[8];
    float* out = (float*)d_out;

    char* ws = (char*)d_ws;
    bf16_t* xb    = (bf16_t*)(ws);                       // 16 MB  (later aliased as Ob)
    bf16_t* WqkvT = (bf16_t*)(ws + (16u << 20));         // 12 MB  (later aliased as Vtb)
    bf16_t* WoT   = (bf16_t*)(ws + (28u << 20));         //  8 MB
    bf16_t* QKVb  = (bf16_t*)(ws + (36u << 20));         // 24 MB
    float*  bqkv  = (float*) (ws + (60u << 20));         // 12 KB
    bf16_t* Vtb   = WqkvT;   // weights dead after QKV GEMM; 4 MB blocked V^T
    bf16_t* Ob    = xb;      // x dead after QKV GEMM

    const float qs = 0.12751707498038074f;   // 1/sqrt(128) * log2(e)

    cvt_f32_bf16<<<(MROWS * DIM) / 1024, 256, 0, stream>>>(x, xb, MROWS * DIM);
    transpose_cvt<<<dim3(DIM / 32, DIM / 32), 256, 0, stream>>>(Wq, WqkvT, DIM, DIM);
    transpose_cvt<<<dim3(KVD / 32, DIM / 32), 256, 0, stream>>>(Wk, WqkvT + (size_t)DIM * DIM, DIM, KVD);
    transpose_cvt<<<dim3(KVD / 32, DIM / 32), 256, 0, stream>>>(Wv, WqkvT + (size_t)(DIM + KVD) * DIM, DIM, KVD);
    transpose_cvt<<<dim3(DIM / 32, DIM / 32), 256, 0, stream>>>(Wo, WoT, DIM, DIM);
    concat_bias<<<(QKVN + 255) / 256, 256, 0, stream>>>(bq, bk, bv, bqkv);

    gemm8p<256, 256, bf16_t><<<dim3((MROWS / 256) * (QKVN / 256)), 512, 0, stream>>>(
        xb, WqkvT, bqkv, QKVb, MROWS, QKVN, DIM, qs, DIM);

    transpose_v<<<dim3(SEQ / 32, KVD / 32, NB), 256, 0, stream>>>(QKVb, Vtb);

    attn_kernel<<<dim3(NB * NKVH * (SEQ / 16)), 256, 0, stream>>>(QKVb, Vtb, Ob);

    gemm8p<128, 256, float><<<dim3((MROWS / 128) * (DIM / 256)), 512, 0, stream>>>(
        Ob, WoT, bo, out, MROWS, DIM, DIM, 1.0f, 0);
}